// Round 9
// baseline (576.040 us; speedup 1.0000x reference)
//
#include <hip/hip_runtime.h>
#include <stdint.h>

#define B_DIM 2
#define S_DIM 4096
#define D_DIM 1024
#define N_DIM 16
#define ROWS  8192      // B*S
#define NCH   32        // scan chunks
#define CHUNK 128       // S / NCH

typedef unsigned short ushort_t;
typedef unsigned int u32;
typedef __bf16  bf16x8 __attribute__((ext_vector_type(8)));
typedef float   f32x4  __attribute__((ext_vector_type(4)));
typedef ushort_t u16x8 __attribute__((ext_vector_type(8)));

__device__ __forceinline__ float b2f(ushort_t u) {
    union { float f; u32 i; } v; v.i = ((u32)u) << 16; return v.f;
}
__device__ __forceinline__ ushort_t f2b(float f) {
    union { float f; u32 i; } v; v.f = f;
    u32 r = (v.i + 0x7FFFu + ((v.i >> 16) & 1u)) >> 16;
    return (ushort_t)r;
}
__device__ __forceinline__ float silu_f(float x) { return x / (1.f + __expf(-x)); }

// ---------------------------------------------------------------------------
// fp32 -> bf16 (RNE) conversion for MFMA operands.
// ---------------------------------------------------------------------------
__global__ __launch_bounds__(256) void cvt_k(const float* __restrict__ src,
                                             ushort_t* __restrict__ dst, u32 n)
{
    u32 i = blockIdx.x * 256 + threadIdx.x;
    const u32 stride = gridDim.x * 256;
    for (; i < n; i += stride) dst[i] = f2b(src[i]);
}

// ---------------------------------------------------------------------------
// GEMM (NT): C[M][N] = A[M][K] * B[N][K]^T, bf16 in, fp32 accum.
// CT = ushort_t (bf16 store) or float (fp32 store).
// 128x128 tile, BK=32, 4 waves (2x2 of 64x64), 16x16x32 MFMA. Reg-staged LDS.
// ---------------------------------------------------------------------------
#define TM 128
#define TN 128
#define TK 32

template <typename CT>
__global__ __launch_bounds__(256) void gemm_nt(
    const ushort_t* __restrict__ A, const ushort_t* __restrict__ B,
    CT* __restrict__ C, int M, int N, int K)
{
    __shared__ __align__(16) ushort_t lA[TM * TK];
    __shared__ __align__(16) ushort_t lB[TN * TK];
    const int t    = threadIdx.x;
    const int m0   = blockIdx.y * TM;
    const int n0   = blockIdx.x * TN;
    const int lane = t & 63;
    const int wv   = t >> 6;
    const int wm   = (wv >> 1) * 64;
    const int wn   = (wv & 1) * 64;
    const int fl   = lane & 15;
    const int fg   = lane >> 4;

    f32x4 acc[4][4] = {};

    const int srow = t >> 2;
    const int scol = (t & 3) * 8;
    const size_t aBase = (size_t)(m0 + srow) * K + scol;
    const size_t bBase = (size_t)(n0 + srow) * K + scol;

    u16x8* sA = (u16x8*)lA;
    u16x8* sB = (u16x8*)lB;

    for (int k0 = 0; k0 < K; k0 += TK) {
        const u16x8 va0 = *(const u16x8*)(A + aBase + k0);
        const u16x8 va1 = *(const u16x8*)(A + aBase + k0 + (size_t)64 * K);
        const u16x8 vb0 = *(const u16x8*)(B + bBase + k0);
        const u16x8 vb1 = *(const u16x8*)(B + bBase + k0 + (size_t)64 * K);
        __syncthreads();
        sA[t]       = va0;
        sA[t + 256] = va1;
        sB[t]       = vb0;
        sB[t + 256] = vb1;
        __syncthreads();

        bf16x8 af[4], bff[4];
#pragma unroll
        for (int i = 0; i < 4; ++i) {
            af[i]  = *(const bf16x8*)&lA[(wm + i * 16 + fl) * TK + fg * 8];
            bff[i] = *(const bf16x8*)&lB[(wn + i * 16 + fl) * TK + fg * 8];
        }
#pragma unroll
        for (int mi = 0; mi < 4; ++mi)
#pragma unroll
            for (int ni = 0; ni < 4; ++ni)
                acc[mi][ni] = __builtin_amdgcn_mfma_f32_16x16x32_bf16(
                    af[mi], bff[ni], acc[mi][ni], 0, 0, 0);
    }

    // C/D layout: col = lane&15, row = (lane>>4)*4 + reg  [m89]
#pragma unroll
    for (int mi = 0; mi < 4; ++mi) {
#pragma unroll
        for (int r = 0; r < 4; ++r) {
            const int row = m0 + wm + mi * 16 + fg * 4 + r;
#pragma unroll
            for (int ni = 0; ni < 4; ++ni) {
                const int col = n0 + wn + ni * 16 + fl;
                if constexpr (sizeof(CT) == 2)
                    C[(size_t)row * N + col] = f2b(acc[mi][ni][r]);
                else
                    C[(size_t)row * N + col] = acc[mi][ni][r];
            }
        }
    }
}

// ---------------------------------------------------------------------------
// Depthwise causal conv1d (K=4, left pad 3) + SiLU.  x_in = xz[:, 0:D].
// conv weights read as fp32 [D][1][4].
// ---------------------------------------------------------------------------
__global__ __launch_bounds__(256) void conv_silu_k(
    const ushort_t* __restrict__ xz, const float* __restrict__ cw,
    ushort_t* __restrict__ xc)
{
    const int tid = blockIdx.x * 256 + threadIdx.x;   // ROWS * D/8 threads
    const int dv  = tid & (D_DIM / 8 - 1);
    const int row = tid >> 7;
    const int s   = row & (S_DIM - 1);
    const int d0  = dv * 8;

    float w[4][8];
#pragma unroll
    for (int e = 0; e < 8; ++e) {
        const f32x4 v = *(const f32x4*)(cw + (size_t)(d0 + e) * 4);
#pragma unroll
        for (int k = 0; k < 4; ++k) w[k][e] = v[k];
    }
    float acc[8] = {0, 0, 0, 0, 0, 0, 0, 0};
#pragma unroll
    for (int k = 0; k < 4; ++k) {
        const int sj = s - 3 + k;
        if (sj >= 0) {
            u16x8 v = *(const u16x8*)(xz + (size_t)(row - 3 + k) * (2 * D_DIM) + d0);
#pragma unroll
            for (int e = 0; e < 8; ++e) acc[e] = fmaf(w[k][e], b2f(v[e]), acc[e]);
        }
    }
    u16x8 o;
#pragma unroll
    for (int e = 0; e < 8; ++e) o[e] = f2b(silu_f(acc[e]));
    *(u16x8*)(xc + (size_t)row * D_DIM + d0) = o;
}

// ---------------------------------------------------------------------------
// Fused x_proj (dtBC = xc @ W_x^T) + dt_proj (softplus) per row. 1 wave/row.
// Wx [32][1024], Wdt [1024][16], bdt [1024] read as fp32.
// Stores dt fp32 [ROWS][D] and Bmat fp32 [ROWS][16].
// ---------------------------------------------------------------------------
__global__ __launch_bounds__(64) void xdt_k(
    const ushort_t* __restrict__ xc, const float* __restrict__ Wx,
    const float* __restrict__ Wdt, const float* __restrict__ bdt,
    float* __restrict__ dt, float* __restrict__ Bm)
{
    const int m = blockIdx.x;
    const int l = threadIdx.x;
    const int j = l >> 1, h = l & 1;          // output col 0..31, K-half

    const ushort_t* xr = xc + (size_t)m * D_DIM + h * 512;
    const float*    wr = Wx + (size_t)j * D_DIM + h * 512;
    float s = 0.f;
    for (int k = 0; k < 512; k += 8) {
        u16x8 a  = *(const u16x8*)(xr + k);
        f32x4 b0 = *(const f32x4*)(wr + k);
        f32x4 b1 = *(const f32x4*)(wr + k + 4);
#pragma unroll
        for (int e = 0; e < 4; ++e) s = fmaf(b2f(a[e]), b0[e], s);
#pragma unroll
        for (int e = 0; e < 4; ++e) s = fmaf(b2f(a[4 + e]), b1[e], s);
    }
    s += __shfl_xor(s, 1);

    __shared__ float vbuf[32];
    if (h == 0) vbuf[j] = s;
    __syncthreads();

    if (l < 16) Bm[(size_t)m * 16 + l] = vbuf[16 + l];

    float vn[16];
#pragma unroll
    for (int n = 0; n < 16; ++n) vn[n] = vbuf[n];

#pragma unroll
    for (int jj = 0; jj < 16; ++jj) {
        const int d = jj * 64 + l;
        const float* wd = Wdt + (size_t)d * 16;
        float a = bdt[d];
#pragma unroll
        for (int n = 0; n < 16; n += 4) {
            const f32x4 wv = *(const f32x4*)(wd + n);
            a = fmaf(vn[n], wv[0], a);
            a = fmaf(vn[n + 1], wv[1], a);
            a = fmaf(vn[n + 2], wv[2], a);
            a = fmaf(vn[n + 3], wv[3], a);
        }
        const float sp = (a > 20.f) ? a : log1pf(__expf(a));
        dt[(size_t)m * D_DIM + d] = sp;
    }
}

// ---------------------------------------------------------------------------
// Scan pass 1: per (b, d-block64, chunk) compute per-chunk transfer (Ac, Bc):
// h_out = Ac * h_in + Bc.  lane = (d_local 16) x (n-group 4), 4 n per lane.
// Alog read as fp32 [D][16].
// ---------------------------------------------------------------------------
__global__ __launch_bounds__(256) void scan1_k(
    const float* __restrict__ dt, const float* __restrict__ Bm,
    const ushort_t* __restrict__ xc, const float* __restrict__ Alog,
    float* __restrict__ Ac, float* __restrict__ Bc)
{
    const int bid  = blockIdx.x;          // [b:1][dblk:4][c:5]
    const int c    = bid & (NCH - 1);
    const int dblk = (bid >> 5) & 15;
    const int b    = bid >> 9;
    const int t    = threadIdx.x;
    const int l    = t & 63, wv = t >> 6;
    const int dl   = l & 15, ng = l >> 4;
    const int d    = dblk * 64 + wv * 16 + dl;

    float Ak[4];
#pragma unroll
    for (int r = 0; r < 4; ++r)
        Ak[r] = -__expf(Alog[(size_t)d * 16 + ng * 4 + r]) * 1.44269504f;

    float h0 = 0, h1 = 0, h2 = 0, h3 = 0, sdt = 0;
    const size_t rowBase = (size_t)b * S_DIM + (size_t)c * CHUNK;
#pragma unroll 4
    for (int s = 0; s < CHUNK; ++s) {
        const size_t row = rowBase + s;
        const float dtv = dt[row * D_DIM + d];
        const float xv  = b2f(xc[row * D_DIM + d]);
        const f32x4 Bv  = *(const f32x4*)(Bm + row * 16 + ng * 4);
        sdt += dtv;
        h0 = fmaf(exp2f(Ak[0] * dtv), h0, Bv[0] * xv);
        h1 = fmaf(exp2f(Ak[1] * dtv), h1, Bv[1] * xv);
        h2 = fmaf(exp2f(Ak[2] * dtv), h2, Bv[2] * xv);
        h3 = fmaf(exp2f(Ak[3] * dtv), h3, Bv[3] * xv);
    }
    const size_t idx = ((((size_t)b * D_DIM + d) * NCH + c) * 16) + ng * 4;
    f32x4 av; av[0] = exp2f(Ak[0] * sdt); av[1] = exp2f(Ak[1] * sdt);
    av[2] = exp2f(Ak[2] * sdt); av[3] = exp2f(Ak[3] * sdt);
    f32x4 bv; bv[0] = h0; bv[1] = h1; bv[2] = h2; bv[3] = h3;
    *(f32x4*)(Ac + idx) = av;
    *(f32x4*)(Bc + idx) = bv;
}

// ---------------------------------------------------------------------------
// Scan pass 2: chunk-prefix combine + recompute + y = sum_n h + gate.
// g = y * silu(z) stored bf16 (gemm2 A-operand).
// ---------------------------------------------------------------------------
__global__ __launch_bounds__(256) void scan2_k(
    const float* __restrict__ dt, const float* __restrict__ Bm,
    const ushort_t* __restrict__ xc, const float* __restrict__ Alog,
    const float* __restrict__ Ac, const float* __restrict__ Bc,
    const ushort_t* __restrict__ xz, ushort_t* __restrict__ g)
{
    const int bid  = blockIdx.x;
    const int c    = bid & (NCH - 1);
    const int dblk = (bid >> 5) & 15;
    const int b    = bid >> 9;
    const int t    = threadIdx.x;
    const int l    = t & 63, wv = t >> 6;
    const int dl   = l & 15, ng = l >> 4;
    const int d    = dblk * 64 + wv * 16 + dl;

    float Ak[4];
#pragma unroll
    for (int r = 0; r < 4; ++r)
        Ak[r] = -__expf(Alog[(size_t)d * 16 + ng * 4 + r]) * 1.44269504f;

    float h0 = 0, h1 = 0, h2 = 0, h3 = 0;
    const size_t base = (((size_t)b * D_DIM + d) * NCH) * 16 + ng * 4;
    for (int cc = 0; cc < c; ++cc) {
        const f32x4 av = *(const f32x4*)(Ac + base + (size_t)cc * 16);
        const f32x4 bv = *(const f32x4*)(Bc + base + (size_t)cc * 16);
        h0 = fmaf(av[0], h0, bv[0]);
        h1 = fmaf(av[1], h1, bv[1]);
        h2 = fmaf(av[2], h2, bv[2]);
        h3 = fmaf(av[3], h3, bv[3]);
    }

    const size_t rowBase = (size_t)b * S_DIM + (size_t)c * CHUNK;
#pragma unroll 4
    for (int s = 0; s < CHUNK; ++s) {
        const size_t row = rowBase + s;
        const float dtv = dt[row * D_DIM + d];
        const float xv  = b2f(xc[row * D_DIM + d]);
        const f32x4 Bv  = *(const f32x4*)(Bm + row * 16 + ng * 4);
        h0 = fmaf(exp2f(Ak[0] * dtv), h0, Bv[0] * xv);
        h1 = fmaf(exp2f(Ak[1] * dtv), h1, Bv[1] * xv);
        h2 = fmaf(exp2f(Ak[2] * dtv), h2, Bv[2] * xv);
        h3 = fmaf(exp2f(Ak[3] * dtv), h3, Bv[3] * xv);
        float ph = (h0 + h1) + (h2 + h3);
        ph += __shfl_xor(ph, 16);
        ph += __shfl_xor(ph, 32);
        if (ng == 0) {
            const float zv = b2f(xz[row * (2 * D_DIM) + D_DIM + d]);
            g[row * D_DIM + d] = f2b(ph * silu_f(zv));
        }
    }
}

// ---------------------------------------------------------------------------
extern "C" void kernel_launch(void* const* d_in, const int* in_sizes, int n_in,
                              void* d_out, int out_size, void* d_ws, size_t ws_size,
                              hipStream_t stream)
{
    // inputs: fp32 (proven on-device round 6: flag-gated cvt eliminated NaN)
    const float* xf    = (const float*)d_in[0];
    const float* Winf  = (const float*)d_in[1];
    const float* convw = (const float*)d_in[2];
    const float* Wx    = (const float*)d_in[3];
    const float* Wdt   = (const float*)d_in[4];
    const float* bdt   = (const float*)d_in[5];
    const float* Alog  = (const float*)d_in[6];
    const float* Woutf = (const float*)d_in[7];
    float* out = (float*)d_out;   // reference output fp32

    char* ws = (char*)d_ws;
    ushort_t* xz = (ushort_t*)(ws + 0);                 // [8192][2048] bf16  33.55MB
    ushort_t* xc = (ushort_t*)(ws + 33554432);          // [8192][1024] bf16  16.78MB
    float*    dt = (float*)   (ws + 50331648);          // [8192][1024] f32   33.55MB
    float*    Bm = (float*)   (ws + 83886080);          // [8192][16]   f32    0.52MB
    float*    Ac = (float*)   (ws + 84410368);          // [2][1024][32][16]   4.19MB
    float*    Bc = (float*)   (ws + 88604672);          // [2][1024][32][16]   4.19MB
    ushort_t* gg = (ushort_t*)(ws + 92798976);          // [8192][1024] bf16  16.78MB
    // bf16-converted MFMA operands (total ws top 132.64MB — fits the >=132.79MB
    // budget proven in round 6)
    ushort_t* xb    = (ushort_t*)(ws + 109576192);      // 16.78MB
    ushort_t* Winb  = (ushort_t*)(ws + 126353408);      //  4.19MB
    ushort_t* Woutb = (ushort_t*)(ws + 130547712);      //  2.10MB

    // 0) convert MFMA operands fp32 -> bf16
    cvt_k<<<dim3(2048), dim3(256), 0, stream>>>(xf,    xb,    8388608u);
    cvt_k<<<dim3(1024), dim3(256), 0, stream>>>(Winf,  Winb,  2097152u);
    cvt_k<<<dim3(512),  dim3(256), 0, stream>>>(Woutf, Woutb, 1048576u);

    // 1) xz = x @ W_in^T  (bf16 out)
    gemm_nt<ushort_t><<<dim3(2048 / TN, 8192 / TM), dim3(256), 0, stream>>>(
        xb, Winb, xz, 8192, 2048, 1024);
    // 2) xc = silu(causal_dwconv(x_in))
    conv_silu_k<<<dim3(ROWS * (D_DIM / 8) / 256), dim3(256), 0, stream>>>(
        xz, convw, xc);
    // 3) dtBC -> dt (softplus, fp32), Bmat (fp32)
    xdt_k<<<dim3(ROWS), dim3(64), 0, stream>>>(xc, Wx, Wdt, bdt, dt, Bm);
    // 4) scan pass 1: per-chunk transfer functions
    scan1_k<<<dim3(B_DIM * 16 * NCH), dim3(256), 0, stream>>>(
        dt, Bm, xc, Alog, Ac, Bc);
    // 5) scan pass 2: chunk prefix + y + gate
    scan2_k<<<dim3(B_DIM * 16 * NCH), dim3(256), 0, stream>>>(
        dt, Bm, xc, Alog, Ac, Bc, xz, gg);
    // 6) out = g @ W_out^T  (fp32 out)
    gemm_nt<float><<<dim3(1024 / TN, 8192 / TM), dim3(256), 0, stream>>>(
        gg, Woutb, out, 8192, 1024, 1024);
}

// Round 12
// 453.235 us; speedup vs baseline: 1.2710x; 1.2710x over previous
//
#include <hip/hip_runtime.h>
#include <stdint.h>

#define B_DIM 2
#define S_DIM 4096
#define D_DIM 1024
#define N_DIM 16
#define ROWS  8192      // B*S
#define NCH   32        // scan chunks
#define CHUNK 128       // S / NCH

typedef unsigned short ushort_t;
typedef unsigned int u32;
typedef __bf16  bf16x8 __attribute__((ext_vector_type(8)));
typedef float   f32x4  __attribute__((ext_vector_type(4)));
typedef ushort_t u16x8 __attribute__((ext_vector_type(8)));

__device__ __forceinline__ float b2f(ushort_t u) {
    union { float f; u32 i; } v; v.i = ((u32)u) << 16; return v.f;
}
__device__ __forceinline__ ushort_t f2b(float f) {
    union { float f; u32 i; } v; v.f = f;
    u32 r = (v.i + 0x7FFFu + ((v.i >> 16) & 1u)) >> 16;
    return (ushort_t)r;
}
__device__ __forceinline__ float silu_f(float x) { return x / (1.f + __expf(-x)); }

// ---------------------------------------------------------------------------
// fp32 -> bf16 (RNE) conversion for MFMA operands.
// ---------------------------------------------------------------------------
__global__ __launch_bounds__(256) void cvt_k(const float* __restrict__ src,
                                             ushort_t* __restrict__ dst, u32 n)
{
    u32 i = blockIdx.x * 256 + threadIdx.x;
    const u32 stride = gridDim.x * 256;
    for (; i < n; i += stride) dst[i] = f2b(src[i]);
}

// ---------------------------------------------------------------------------
// GEMM (NT): C[M][N] = A[M][K] * B[N][K]^T, bf16 in, fp32 accum.
// 128x128 tile, BK=32, 4 waves (2x2 of 64x64), 16x16x32 MFMA. Reg-staged LDS.
// ---------------------------------------------------------------------------
#define TM 128
#define TN 128
#define TK 32

template <typename CT>
__global__ __launch_bounds__(256) void gemm_nt(
    const ushort_t* __restrict__ A, const ushort_t* __restrict__ B,
    CT* __restrict__ C, int M, int N, int K)
{
    __shared__ __align__(16) ushort_t lA[TM * TK];
    __shared__ __align__(16) ushort_t lB[TN * TK];
    const int t    = threadIdx.x;
    const int m0   = blockIdx.y * TM;
    const int n0   = blockIdx.x * TN;
    const int lane = t & 63;
    const int wv   = t >> 6;
    const int wm   = (wv >> 1) * 64;
    const int wn   = (wv & 1) * 64;
    const int fl   = lane & 15;
    const int fg   = lane >> 4;

    f32x4 acc[4][4] = {};

    const int srow = t >> 2;
    const int scol = (t & 3) * 8;
    const size_t aBase = (size_t)(m0 + srow) * K + scol;
    const size_t bBase = (size_t)(n0 + srow) * K + scol;

    u16x8* sA = (u16x8*)lA;
    u16x8* sB = (u16x8*)lB;

    for (int k0 = 0; k0 < K; k0 += TK) {
        const u16x8 va0 = *(const u16x8*)(A + aBase + k0);
        const u16x8 va1 = *(const u16x8*)(A + aBase + k0 + (size_t)64 * K);
        const u16x8 vb0 = *(const u16x8*)(B + bBase + k0);
        const u16x8 vb1 = *(const u16x8*)(B + bBase + k0 + (size_t)64 * K);
        __syncthreads();
        sA[t]       = va0;
        sA[t + 256] = va1;
        sB[t]       = vb0;
        sB[t + 256] = vb1;
        __syncthreads();

        bf16x8 af[4], bff[4];
#pragma unroll
        for (int i = 0; i < 4; ++i) {
            af[i]  = *(const bf16x8*)&lA[(wm + i * 16 + fl) * TK + fg * 8];
            bff[i] = *(const bf16x8*)&lB[(wn + i * 16 + fl) * TK + fg * 8];
        }
#pragma unroll
        for (int mi = 0; mi < 4; ++mi)
#pragma unroll
            for (int ni = 0; ni < 4; ++ni)
                acc[mi][ni] = __builtin_amdgcn_mfma_f32_16x16x32_bf16(
                    af[mi], bff[ni], acc[mi][ni], 0, 0, 0);
    }

    // C/D layout: col = lane&15, row = (lane>>4)*4 + reg  [m89]
#pragma unroll
    for (int mi = 0; mi < 4; ++mi) {
#pragma unroll
        for (int r = 0; r < 4; ++r) {
            const int row = m0 + wm + mi * 16 + fg * 4 + r;
#pragma unroll
            for (int ni = 0; ni < 4; ++ni) {
                const int col = n0 + wn + ni * 16 + fl;
                if constexpr (sizeof(CT) == 2)
                    C[(size_t)row * N + col] = f2b(acc[mi][ni][r]);
                else
                    C[(size_t)row * N + col] = acc[mi][ni][r];
            }
        }
    }
}

// ---------------------------------------------------------------------------
// dtbc_k: dtBC[8192][32] = xc[8192][1024] @ Wxb[32][1024]^T  (bf16 MFMA).
// TM=128, TN=32, TK=32; 4 waves, each 32 rows (2 M-frags x 2 N-frags).
// Same NT fragment scheme as gemm_nt (k-permutation cancels; C/D layout m89).
// ---------------------------------------------------------------------------
__global__ __launch_bounds__(256) void dtbc_k(
    const ushort_t* __restrict__ xc, const ushort_t* __restrict__ Wxb,
    float* __restrict__ dtBC)
{
    __shared__ __align__(16) ushort_t lA[128 * 32];   // 8 KB
    __shared__ __align__(16) ushort_t lB[32 * 32];    // 2 KB
    const int t    = threadIdx.x;
    const int m0   = blockIdx.x * 128;
    const int lane = t & 63;
    const int wv   = t >> 6;
    const int wm   = wv * 32;
    const int fl   = lane & 15;
    const int fg   = lane >> 4;

    f32x4 acc[2][2] = {};

    const int srow = t >> 2;          // 0..63
    const int scol = (t & 3) * 8;
    const size_t aBase = (size_t)(m0 + srow) * 1024 + scol;
    const size_t bBase = (size_t)(srow & 31) * 1024 + scol;   // t<128: rows 0..31

    u16x8* sA = (u16x8*)lA;
    u16x8* sB = (u16x8*)lB;

    for (int k0 = 0; k0 < 1024; k0 += 32) {
        const u16x8 va0 = *(const u16x8*)(xc + aBase + k0);
        const u16x8 va1 = *(const u16x8*)(xc + aBase + k0 + (size_t)64 * 1024);
        u16x8 vb = {};
        if (t < 128) vb = *(const u16x8*)(Wxb + bBase + k0);
        __syncthreads();
        sA[t]       = va0;
        sA[t + 256] = va1;
        if (t < 128) sB[t] = vb;      // idx = (t>>2)*4 + (t&3) = t
        __syncthreads();

        bf16x8 af[2], bf[2];
#pragma unroll
        for (int i = 0; i < 2; ++i) {
            af[i] = *(const bf16x8*)&lA[(wm + i * 16 + fl) * 32 + fg * 8];
            bf[i] = *(const bf16x8*)&lB[(i * 16 + fl) * 32 + fg * 8];
        }
#pragma unroll
        for (int mi = 0; mi < 2; ++mi)
#pragma unroll
            for (int ni = 0; ni < 2; ++ni)
                acc[mi][ni] = __builtin_amdgcn_mfma_f32_16x16x32_bf16(
                    af[mi], bf[ni], acc[mi][ni], 0, 0, 0);
    }

#pragma unroll
    for (int mi = 0; mi < 2; ++mi)
#pragma unroll
        for (int r = 0; r < 4; ++r) {
            const int row = m0 + wm + mi * 16 + fg * 4 + r;
#pragma unroll
            for (int ni = 0; ni < 2; ++ni)
                dtBC[(size_t)row * 32 + ni * 16 + fl] = acc[mi][ni][r];
        }
}

// ---------------------------------------------------------------------------
// dtproj_k: dt[row][d] = softplus(dtBC[row][0:16] . Wdt[d][:] + bdt[d]).
// One thread per output element; v broadcast from L1, Wdt coalesced.
// ---------------------------------------------------------------------------
__global__ __launch_bounds__(256) void dtproj_k(
    const float* __restrict__ dtBC, const float* __restrict__ Wdt,
    const float* __restrict__ bdt, float* __restrict__ dt)
{
    const int bid = blockIdx.x;               // [row:13][dq:2]
    const int row = bid >> 2;
    const int d   = (bid & 3) * 256 + threadIdx.x;

    const float* v = dtBC + (size_t)row * 32;
    const float* wd = Wdt + (size_t)d * 16;
    float a = bdt[d];
#pragma unroll
    for (int n = 0; n < 16; n += 4) {
        const f32x4 vv = *(const f32x4*)(v + n);
        const f32x4 wv = *(const f32x4*)(wd + n);
        a = fmaf(vv[0], wv[0], a);
        a = fmaf(vv[1], wv[1], a);
        a = fmaf(vv[2], wv[2], a);
        a = fmaf(vv[3], wv[3], a);
    }
    const float sp = (a > 20.f) ? a : log1pf(__expf(a));
    dt[(size_t)row * D_DIM + d] = sp;
}

// ---------------------------------------------------------------------------
// Depthwise causal conv1d (K=4, left pad 3) + SiLU.  x_in = xz[:, 0:D].
// ---------------------------------------------------------------------------
__global__ __launch_bounds__(256) void conv_silu_k(
    const ushort_t* __restrict__ xz, const float* __restrict__ cw,
    ushort_t* __restrict__ xc)
{
    const int tid = blockIdx.x * 256 + threadIdx.x;   // ROWS * D/8 threads
    const int dv  = tid & (D_DIM / 8 - 1);
    const int row = tid >> 7;
    const int s   = row & (S_DIM - 1);
    const int d0  = dv * 8;

    float w[4][8];
#pragma unroll
    for (int e = 0; e < 8; ++e) {
        const f32x4 v = *(const f32x4*)(cw + (size_t)(d0 + e) * 4);
#pragma unroll
        for (int k = 0; k < 4; ++k) w[k][e] = v[k];
    }
    float acc[8] = {0, 0, 0, 0, 0, 0, 0, 0};
#pragma unroll
    for (int k = 0; k < 4; ++k) {
        const int sj = s - 3 + k;
        if (sj >= 0) {
            u16x8 v = *(const u16x8*)(xz + (size_t)(row - 3 + k) * (2 * D_DIM) + d0);
#pragma unroll
            for (int e = 0; e < 8; ++e) acc[e] = fmaf(w[k][e], b2f(v[e]), acc[e]);
        }
    }
    u16x8 o;
#pragma unroll
    for (int e = 0; e < 8; ++e) o[e] = f2b(silu_f(acc[e]));
    *(u16x8*)(xc + (size_t)row * D_DIM + d0) = o;
}

// ---------------------------------------------------------------------------
// Scan pass 1: per (b, d-block64, chunk) compute per-chunk transfer (Ac, Bc):
// h_out = Ac * h_in + Bc.  lane = (d_local 16) x (n-group 4), 4 n per lane.
// B-vector read from dtBC[row][16 + n].
// ---------------------------------------------------------------------------
__global__ __launch_bounds__(256) void scan1_k(
    const float* __restrict__ dt, const float* __restrict__ dtBC,
    const ushort_t* __restrict__ xc, const float* __restrict__ Alog,
    float* __restrict__ Ac, float* __restrict__ Bc)
{
    const int bid  = blockIdx.x;          // [b:1][dblk:4][c:5]
    const int c    = bid & (NCH - 1);
    const int dblk = (bid >> 5) & 15;
    const int b    = bid >> 9;
    const int t    = threadIdx.x;
    const int l    = t & 63, wv = t >> 6;
    const int dl   = l & 15, ng = l >> 4;
    const int d    = dblk * 64 + wv * 16 + dl;

    float Ak[4];
#pragma unroll
    for (int r = 0; r < 4; ++r)
        Ak[r] = -__expf(Alog[(size_t)d * 16 + ng * 4 + r]) * 1.44269504f;

    float h0 = 0, h1 = 0, h2 = 0, h3 = 0, sdt = 0;
    const size_t rowBase = (size_t)b * S_DIM + (size_t)c * CHUNK;
#pragma unroll 4
    for (int s = 0; s < CHUNK; ++s) {
        const size_t row = rowBase + s;
        const float dtv = dt[row * D_DIM + d];
        const float xv  = b2f(xc[row * D_DIM + d]);
        const f32x4 Bv  = *(const f32x4*)(dtBC + row * 32 + 16 + ng * 4);
        sdt += dtv;
        h0 = fmaf(exp2f(Ak[0] * dtv), h0, Bv[0] * xv);
        h1 = fmaf(exp2f(Ak[1] * dtv), h1, Bv[1] * xv);
        h2 = fmaf(exp2f(Ak[2] * dtv), h2, Bv[2] * xv);
        h3 = fmaf(exp2f(Ak[3] * dtv), h3, Bv[3] * xv);
    }
    const size_t idx = ((((size_t)b * D_DIM + d) * NCH + c) * 16) + ng * 4;
    f32x4 av; av[0] = exp2f(Ak[0] * sdt); av[1] = exp2f(Ak[1] * sdt);
    av[2] = exp2f(Ak[2] * sdt); av[3] = exp2f(Ak[3] * sdt);
    f32x4 bv; bv[0] = h0; bv[1] = h1; bv[2] = h2; bv[3] = h3;
    *(f32x4*)(Ac + idx) = av;
    *(f32x4*)(Bc + idx) = bv;
}

// ---------------------------------------------------------------------------
// Scan pass 2: chunk-prefix combine + recompute + y = sum_n h + gate.
// g = y * silu(z) stored bf16 (gemm2 A-operand).
// ---------------------------------------------------------------------------
__global__ __launch_bounds__(256) void scan2_k(
    const float* __restrict__ dt, const float* __restrict__ dtBC,
    const ushort_t* __restrict__ xc, const float* __restrict__ Alog,
    const float* __restrict__ Ac, const float* __restrict__ Bc,
    const ushort_t* __restrict__ xz, ushort_t* __restrict__ g)
{
    const int bid  = blockIdx.x;
    const int c    = bid & (NCH - 1);
    const int dblk = (bid >> 5) & 15;
    const int b    = bid >> 9;
    const int t    = threadIdx.x;
    const int l    = t & 63, wv = t >> 6;
    const int dl   = l & 15, ng = l >> 4;
    const int d    = dblk * 64 + wv * 16 + dl;

    float Ak[4];
#pragma unroll
    for (int r = 0; r < 4; ++r)
        Ak[r] = -__expf(Alog[(size_t)d * 16 + ng * 4 + r]) * 1.44269504f;

    float h0 = 0, h1 = 0, h2 = 0, h3 = 0;
    const size_t base = (((size_t)b * D_DIM + d) * NCH) * 16 + ng * 4;
    for (int cc = 0; cc < c; ++cc) {
        const f32x4 av = *(const f32x4*)(Ac + base + (size_t)cc * 16);
        const f32x4 bv = *(const f32x4*)(Bc + base + (size_t)cc * 16);
        h0 = fmaf(av[0], h0, bv[0]);
        h1 = fmaf(av[1], h1, bv[1]);
        h2 = fmaf(av[2], h2, bv[2]);
        h3 = fmaf(av[3], h3, bv[3]);
    }

    const size_t rowBase = (size_t)b * S_DIM + (size_t)c * CHUNK;
#pragma unroll 4
    for (int s = 0; s < CHUNK; ++s) {
        const size_t row = rowBase + s;
        const float dtv = dt[row * D_DIM + d];
        const float xv  = b2f(xc[row * D_DIM + d]);
        const f32x4 Bv  = *(const f32x4*)(dtBC + row * 32 + 16 + ng * 4);
        h0 = fmaf(exp2f(Ak[0] * dtv), h0, Bv[0] * xv);
        h1 = fmaf(exp2f(Ak[1] * dtv), h1, Bv[1] * xv);
        h2 = fmaf(exp2f(Ak[2] * dtv), h2, Bv[2] * xv);
        h3 = fmaf(exp2f(Ak[3] * dtv), h3, Bv[3] * xv);
        float ph = (h0 + h1) + (h2 + h3);
        ph += __shfl_xor(ph, 16);
        ph += __shfl_xor(ph, 32);
        if (ng == 0) {
            const float zv = b2f(xz[row * (2 * D_DIM) + D_DIM + d]);
            g[row * D_DIM + d] = f2b(ph * silu_f(zv));
        }
    }
}

// ---------------------------------------------------------------------------
extern "C" void kernel_launch(void* const* d_in, const int* in_sizes, int n_in,
                              void* d_out, int out_size, void* d_ws, size_t ws_size,
                              hipStream_t stream)
{
    // inputs: fp32 (proven on-device round 6)
    const float* xf    = (const float*)d_in[0];
    const float* Winf  = (const float*)d_in[1];
    const float* convw = (const float*)d_in[2];
    const float* Wx    = (const float*)d_in[3];
    const float* Wdt   = (const float*)d_in[4];
    const float* bdt   = (const float*)d_in[5];
    const float* Alog  = (const float*)d_in[6];
    const float* Woutf = (const float*)d_in[7];
    float* out = (float*)d_out;   // reference output fp32

    char* ws = (char*)d_ws;
    ushort_t* xz = (ushort_t*)(ws + 0);                 // [8192][2048] bf16  33.55MB
    ushort_t* xc = (ushort_t*)(ws + 33554432);          // [8192][1024] bf16  16.78MB
    float*    dt = (float*)   (ws + 50331648);          // [8192][1024] f32   33.55MB
    float*    Ac = (float*)   (ws + 84410368);          // [2][1024][32][16]   4.19MB
    float*    Bc = (float*)   (ws + 88604672);          // [2][1024][32][16]   4.19MB
    ushort_t* gg = (ushort_t*)(ws + 92798976);          // [8192][1024] bf16  16.78MB
    // bf16-converted MFMA operands
    ushort_t* xb    = (ushort_t*)(ws + 109576192);      // 16.78MB (dead after gemm1)
    ushort_t* Winb  = (ushort_t*)(ws + 126353408);      //  4.19MB
    ushort_t* Woutb = (ushort_t*)(ws + 130547712);      //  2.10MB
    ushort_t* Wxb   = (ushort_t*)(ws + 132644864);      // 64KB (top 132.71MB, proven)
    // dtBC [8192][32] f32 reuses xb's region (xb dead after gemm1)
    float*    dtBC  = (float*)  (ws + 109576192);       //  1.05MB

    // 0) convert MFMA operands fp32 -> bf16
    cvt_k<<<dim3(2048), dim3(256), 0, stream>>>(xf,    xb,    8388608u);
    cvt_k<<<dim3(1024), dim3(256), 0, stream>>>(Winf,  Winb,  2097152u);
    cvt_k<<<dim3(512),  dim3(256), 0, stream>>>(Woutf, Woutb, 1048576u);
    cvt_k<<<dim3(32),   dim3(256), 0, stream>>>(Wx,    Wxb,     32768u);

    // 1) xz = x @ W_in^T  (bf16 out)
    gemm_nt<ushort_t><<<dim3(2048 / TN, 8192 / TM), dim3(256), 0, stream>>>(
        xb, Winb, xz, 8192, 2048, 1024);
    // 2) xc = silu(causal_dwconv(x_in))
    conv_silu_k<<<dim3(ROWS * (D_DIM / 8) / 256), dim3(256), 0, stream>>>(
        xz, convw, xc);
    // 3a) dtBC = xc @ Wx^T  (MFMA; overwrites dead xb region)
    dtbc_k<<<dim3(ROWS / 128), dim3(256), 0, stream>>>(xc, Wxb, dtBC);
    // 3b) dt = softplus(dtBC[:, :16] @ Wdt^T + bdt)
    dtproj_k<<<dim3(ROWS * 4), dim3(256), 0, stream>>>(dtBC, Wdt, bdt, dt);
    // 4) scan pass 1: per-chunk transfer functions
    scan1_k<<<dim3(B_DIM * 16 * NCH), dim3(256), 0, stream>>>(
        dt, dtBC, xc, Alog, Ac, Bc);
    // 5) scan pass 2: chunk prefix + y + gate
    scan2_k<<<dim3(B_DIM * 16 * NCH), dim3(256), 0, stream>>>(
        dt, dtBC, xc, Alog, Ac, Bc, xz, gg);
    // 6) out = g @ W_out^T  (fp32 out)
    gemm_nt<float><<<dim3(1024 / TN, 8192 / TM), dim3(256), 0, stream>>>(
        gg, Woutb, out, 8192, 1024, 1024);
}